// Round 5
// baseline (827.545 us; speedup 1.0000x reference)
//
#include <hip/hip_runtime.h>

#define NFEAT 128
#define NHID 64
#define NCLASS 40

#define BSH 8                    // CSR-build bin = 256 nodes
#define MAXBIN 512               // supports N <= 131072
#define CH 8192                  // edges per chunk in pass A
#define PBSH 15                  // src phase-bucket = 32768 nodes (<=3.2MB of 64-wide bf16 rows)
#define NPH 4                    // phase buckets

// ---------------- bf16 helpers (storage-only precision; compute is fp32) ----------------

__device__ __forceinline__ float bfu(unsigned short u) {
    return __uint_as_float((unsigned)u << 16);
}
__device__ __forceinline__ unsigned short fbf(float f) {
    unsigned u = __float_as_uint(f);
    u += 0x7fffu + ((u >> 16) & 1u);        // round-to-nearest-even
    return (unsigned short)(u >> 16);
}

// ======================= CSR build, hierarchical =======================

__launch_bounds__(256)
__global__ void binA1(const int* __restrict__ dst, int* __restrict__ gcount, int E, int nbin) {
    __shared__ int h[MAXBIN];
    const int t = threadIdx.x;
    for (int i = t; i < nbin; i += 256) h[i] = 0;
    __syncthreads();
    const int e0 = blockIdx.x * CH;
    const int e1 = min(e0 + CH, E);
    for (int i = e0 + t; i < e1; i += 256) atomicAdd(&h[dst[i] >> BSH], 1);
    __syncthreads();
    for (int i = t; i < nbin; i += 256) { int c = h[i]; if (c) atomicAdd(&gcount[i], c); }
}

__launch_bounds__(512)
__global__ void binscan(const int* __restrict__ gcount, int* __restrict__ gbase,
                        int* __restrict__ gcur, int* __restrict__ rp2,
                        int nbin, int N, int E) {
    __shared__ int sd[512];
    const int t = threadIdx.x;
    int v = (t < nbin) ? gcount[t] : 0;
    sd[t] = v;
    __syncthreads();
    for (int off = 1; off < 512; off <<= 1) {
        int tmp = (t >= off) ? sd[t - off] : 0;
        __syncthreads();
        sd[t] += tmp;
        __syncthreads();
    }
    int excl = sd[t] - v;
    if (t < nbin) { gbase[t] = excl; gcur[t] = excl; }
    if (t == 0) { gbase[nbin] = E; rp2[4 * (size_t)N] = E; }
}

// A2: reserve a contiguous run per bin, scatter packed (local_dst<<24 | src).
__launch_bounds__(256)
__global__ void binA2(const int* __restrict__ src, const int* __restrict__ dst,
                      int* __restrict__ gcur, unsigned* __restrict__ ebuf, int E, int nbin) {
    __shared__ int h[MAXBIN];
    __shared__ int base[MAXBIN];
    const int t = threadIdx.x;
    for (int i = t; i < nbin; i += 256) h[i] = 0;
    __syncthreads();
    const int e0 = blockIdx.x * CH;
    const int e1 = min(e0 + CH, E);
    for (int i = e0 + t; i < e1; i += 256) atomicAdd(&h[dst[i] >> BSH], 1);
    __syncthreads();
    for (int i = t; i < nbin; i += 256) {
        int c = h[i];
        if (c) base[i] = atomicAdd(&gcur[i], c);
        h[i] = 0;
    }
    __syncthreads();
    for (int i = e0 + t; i < e1; i += 256) {
        int d = dst[i];
        int b = d >> BSH;
        int pos = base[b] + atomicAdd(&h[b], 1);
        ebuf[pos] = ((unsigned)(d & ((1 << BSH) - 1)) << 24) | (unsigned)src[i];
    }
}

// B: one wg per 256-node bin. Sorts edges by (node, src-phase-bucket), emits
// rp2[4n+j] boundaries + dinv + csr_src. Key = local_dst*4 + (src>>PBSH).
__launch_bounds__(256)
__global__ void binB(const unsigned* __restrict__ ebuf, const int* __restrict__ gbase,
                     int* __restrict__ rp2, float* __restrict__ dinv,
                     int* __restrict__ csr_src, int N) {
    __shared__ int cnt[1024];
    __shared__ int sd[256];
    const int b = blockIdx.x;
    const int n0 = b << BSH;
    const int t = threadIdx.x;
    const int b0 = gbase[b], b1 = gbase[b + 1];
    #pragma unroll
    for (int j = 0; j < 4; ++j) cnt[4 * t + j] = 0;
    __syncthreads();
    for (int i = b0 + t; i < b1; i += 256) {
        unsigned p = ebuf[i];
        int key = ((p >> 24) << 2) | ((p & 0xffffffu) >> PBSH);
        atomicAdd(&cnt[key], 1);
    }
    __syncthreads();
    int c[4]; int tot = 0;
    #pragma unroll
    for (int j = 0; j < 4; ++j) { c[j] = cnt[4 * t + j]; tot += c[j]; }
    sd[t] = tot;
    __syncthreads();
    for (int off = 1; off < 256; off <<= 1) {
        int v = (t >= off) ? sd[t - off] : 0;
        __syncthreads();
        sd[t] += v;
        __syncthreads();
    }
    int excl = sd[t] - tot;
    int n = n0 + t;
    int run = b0 + excl;
    #pragma unroll
    for (int j = 0; j < 4; ++j) {
        if (n < N) rp2[4 * (size_t)n + j] = run;
        cnt[4 * t + j] = run;                 // reuse as cursor
        run += c[j];
    }
    if (n < N) dinv[n] = rsqrtf((float)tot + 1.0f);   // +1 self loop
    __syncthreads();
    for (int i = b0 + t; i < b1; i += 256) {
        unsigned p = ebuf[i];
        int key = ((p >> 24) << 2) | ((p & 0xffffffu) >> PBSH);
        int pos = atomicAdd(&cnt[key], 1);
        csr_src[pos] = (int)(p & 0xffffffu);
    }
}

// ======================= dense linear =======================
// out[n,:] = bf16( dinv[n] * (f(in[n,:]) @ W) ), f = relu(x + bias_prev) if RELU_BIAS.

template<int K, int F, bool RELU_BIAS, bool IN_BF16>
__launch_bounds__(256)
__global__ void lin_kernel(const void* __restrict__ in_, const float* __restrict__ W,
                           const float* __restrict__ bias, const float* __restrict__ dinv,
                           unsigned short* __restrict__ out, int N) {
    constexpr int FT = F / 4;
    constexpr int TG = 256 / FT;
    constexpr int NPT = 4;
    constexpr int NODES = TG * NPT;
    constexpr int KP = K + 4;

    __shared__ alignas(16) float Ws[K * F];
    __shared__ alignas(16) float xs[NODES * KP];

    const int tid = threadIdx.x;
    const int n0 = blockIdx.x * NODES;

    for (int q = tid; q < K * F / 4; q += 256)
        ((float4*)Ws)[q] = ((const float4*)W)[q];

    if constexpr (IN_BF16) {
        const unsigned short* in = (const unsigned short*)in_;
        for (int q = tid; q < NODES * (K / 8); q += 256) {
            int ni = q / (K / 8);
            int c = q - ni * (K / 8);
            int n = n0 + ni;
            float v[8];
            if (n < N) {
                uint4 raw = *(const uint4*)(in + (size_t)n * K + c * 8);
                unsigned rr[4] = {raw.x, raw.y, raw.z, raw.w};
                #pragma unroll
                for (int j = 0; j < 4; ++j) {
                    v[2 * j]     = __uint_as_float(rr[j] << 16);
                    v[2 * j + 1] = __uint_as_float(rr[j] & 0xffff0000u);
                }
            } else {
                #pragma unroll
                for (int j = 0; j < 8; ++j) v[j] = 0.f;
            }
            if constexpr (RELU_BIAS) {
                #pragma unroll
                for (int j = 0; j < 8; ++j) v[j] = fmaxf(v[j] + bias[c * 8 + j], 0.f);
            }
            *(float4*)&xs[ni * KP + c * 8]     = make_float4(v[0], v[1], v[2], v[3]);
            *(float4*)&xs[ni * KP + c * 8 + 4] = make_float4(v[4], v[5], v[6], v[7]);
        }
    } else {
        const float* in = (const float*)in_;
        for (int q = tid; q < NODES * (K / 4); q += 256) {
            int ni = q / (K / 4);
            int kq = q - ni * (K / 4);
            int n = n0 + ni;
            float4 v = make_float4(0.f, 0.f, 0.f, 0.f);
            if (n < N) v = ((const float4*)in)[(size_t)n * (K / 4) + kq];
            if constexpr (RELU_BIAS) {
                float4 b = ((const float4*)bias)[kq];
                v.x = fmaxf(v.x + b.x, 0.f);
                v.y = fmaxf(v.y + b.y, 0.f);
                v.z = fmaxf(v.z + b.z, 0.f);
                v.w = fmaxf(v.w + b.w, 0.f);
            }
            *(float4*)&xs[ni * KP + kq * 4] = v;
        }
    }
    __syncthreads();

    const int tx = tid % FT;
    const int tg = tid / FT;
    if (tg >= TG) return;

    float4 acc[NPT];
    #pragma unroll
    for (int i = 0; i < NPT; ++i) acc[i] = make_float4(0.f, 0.f, 0.f, 0.f);

    #pragma unroll 4
    for (int kq = 0; kq < K / 4; ++kq) {
        float4 w0 = *(const float4*)&Ws[(kq * 4 + 0) * F + tx * 4];
        float4 w1 = *(const float4*)&Ws[(kq * 4 + 1) * F + tx * 4];
        float4 w2 = *(const float4*)&Ws[(kq * 4 + 2) * F + tx * 4];
        float4 w3 = *(const float4*)&Ws[(kq * 4 + 3) * F + tx * 4];
        #pragma unroll
        for (int i = 0; i < NPT; ++i) {
            float4 xv = *(const float4*)&xs[(tg * NPT + i) * KP + kq * 4];
            acc[i].x += xv.x * w0.x + xv.y * w1.x + xv.z * w2.x + xv.w * w3.x;
            acc[i].y += xv.x * w0.y + xv.y * w1.y + xv.z * w2.y + xv.w * w3.y;
            acc[i].z += xv.x * w0.z + xv.y * w1.z + xv.z * w2.z + xv.w * w3.z;
            acc[i].w += xv.x * w0.w + xv.y * w1.w + xv.z * w2.w + xv.w * w3.w;
        }
    }

    #pragma unroll
    for (int i = 0; i < NPT; ++i) {
        int n = n0 + tg * NPT + i;
        if (n < N) {
            float d = dinv[n];
            ushort4 o;
            o.x = fbf(acc[i].x * d);
            o.y = fbf(acc[i].y * d);
            o.z = fbf(acc[i].z * d);
            o.w = fbf(acc[i].w * d);
            *(ushort4*)(out + (size_t)n * F + tx * 4) = o;
        }
    }
}

// ======================= phase-bucketed gather =======================
// Block owns 128 dst nodes (32/wave); LDS fp32 accumulator; bucket-major loop
// so that during phase j every XCD's L2 only holds bucket j (~3.2MB) of the
// feature buffer. No cross-block sync needed: equal-work blocks stay in
// wall-clock lockstep; drift costs speed only, never correctness.

__launch_bounds__(256)
__global__ void gather64p(const unsigned short* __restrict__ g, const float* __restrict__ dinv,
                          const int* __restrict__ rp2, const int* __restrict__ csr_src,
                          unsigned short* __restrict__ out, int N) {
    __shared__ float acc[128][64];              // 32 KB -> 5 blocks/CU
    const int wave = threadIdx.x >> 6;
    const int lane = threadIdx.x & 63;
    const int n0 = blockIdx.x << 7;
    const int r0 = wave << 5;

    #pragma unroll 4
    for (int r = r0; r < r0 + 32; ++r) {        // self-loop init (coalesced)
        int n = n0 + r;
        acc[r][lane] = (n < N) ? bfu(g[(size_t)n * 64 + lane]) : 0.f;
    }
    __syncthreads();

    for (int j = 0; j < NPH; ++j) {
        for (int r = r0; r < r0 + 32; ++r) {
            int n = n0 + r;
            if (n >= N) break;
            int e0 = rp2[4 * (size_t)n + j];
            int e1 = rp2[4 * (size_t)n + j + 1];
            if (e0 == e1) continue;
            float s = 0.f;
            int e = e0;
            for (; e + 4 <= e1; e += 4) {
                int s0 = csr_src[e + 0];
                int s1 = csr_src[e + 1];
                int s2 = csr_src[e + 2];
                int s3 = csr_src[e + 3];
                float v0 = bfu(g[(size_t)s0 * 64 + lane]);
                float v1 = bfu(g[(size_t)s1 * 64 + lane]);
                float v2 = bfu(g[(size_t)s2 * 64 + lane]);
                float v3 = bfu(g[(size_t)s3 * 64 + lane]);
                s += (v0 + v1) + (v2 + v3);
            }
            for (; e < e1; ++e) s += bfu(g[(size_t)csr_src[e] * 64 + lane]);
            acc[r][lane] += s;
        }
        __syncthreads();                        // block-level phase alignment
    }

    #pragma unroll 4
    for (int r = r0; r < r0 + 32; ++r) {
        int n = n0 + r;
        if (n < N) out[(size_t)n * 64 + lane] = fbf(dinv[n] * acc[r][lane]);
    }
}

// Layer-3: phase-bucketed gather on 40-wide rows + fused bias + log_softmax.
__launch_bounds__(256)
__global__ void gather40p_lsm(const unsigned short* __restrict__ g, const float* __restrict__ dinv,
                              const int* __restrict__ rp2, const int* __restrict__ csr_src,
                              const float* __restrict__ b3, float* __restrict__ out, int N) {
    __shared__ float acc[128][NCLASS];          // 20 KB
    const int wave = threadIdx.x >> 6;
    const int lane = threadIdx.x & 63;
    const int n0 = blockIdx.x << 7;
    const int r0 = wave << 5;
    const int l = min(lane, NCLASS - 1);        // clamped dup for lanes 40..63

    #pragma unroll 4
    for (int r = r0; r < r0 + 32; ++r) {
        int n = n0 + r;
        if (lane < NCLASS) acc[r][lane] = (n < N) ? bfu(g[(size_t)n * NCLASS + lane]) : 0.f;
    }
    __syncthreads();

    for (int j = 0; j < NPH; ++j) {
        for (int r = r0; r < r0 + 32; ++r) {
            int n = n0 + r;
            if (n >= N) break;
            int e0 = rp2[4 * (size_t)n + j];
            int e1 = rp2[4 * (size_t)n + j + 1];
            if (e0 == e1) continue;
            float s = 0.f;
            int e = e0;
            for (; e + 4 <= e1; e += 4) {
                int s0 = csr_src[e + 0];
                int s1 = csr_src[e + 1];
                int s2 = csr_src[e + 2];
                int s3 = csr_src[e + 3];
                float v0 = bfu(g[(size_t)s0 * NCLASS + l]);
                float v1 = bfu(g[(size_t)s1 * NCLASS + l]);
                float v2 = bfu(g[(size_t)s2 * NCLASS + l]);
                float v3 = bfu(g[(size_t)s3 * NCLASS + l]);
                s += (v0 + v1) + (v2 + v3);
            }
            for (; e < e1; ++e) s += bfu(g[(size_t)csr_src[e] * NCLASS + l]);
            if (lane < NCLASS) acc[r][lane] += s;
        }
        __syncthreads();
    }

    for (int r = r0; r < r0 + 32; ++r) {        // fused bias + log_softmax
        int n = n0 + r;
        if (n >= N) break;
        float v = (lane < NCLASS) ? dinv[n] * acc[r][lane] + b3[lane] : -1e30f;
        float mx = v;
        #pragma unroll
        for (int off = 32; off > 0; off >>= 1)
            mx = fmaxf(mx, __shfl_xor(mx, off, 64));
        float ex = (lane < NCLASS) ? expf(v - mx) : 0.f;
        float sm = ex;
        #pragma unroll
        for (int off = 32; off > 0; off >>= 1)
            sm += __shfl_xor(sm, off, 64);
        if (lane < NCLASS) out[(size_t)n * NCLASS + lane] = v - mx - logf(sm);
    }
}

// ======================= launch =======================

extern "C" void kernel_launch(void* const* d_in, const int* in_sizes, int n_in,
                              void* d_out, int out_size, void* d_ws, size_t ws_size,
                              hipStream_t stream) {
    const float* x  = (const float*)d_in[0];
    const int*   ei = (const int*)  d_in[1];
    const float* W1 = (const float*)d_in[2];
    const float* b1 = (const float*)d_in[3];
    const float* W2 = (const float*)d_in[4];
    const float* b2 = (const float*)d_in[5];
    const float* W3 = (const float*)d_in[6];
    const float* b3 = (const float*)d_in[7];
    const int N = in_sizes[0] / NFEAT;
    const int E = in_sizes[1] / 2;
    const int* src = ei;
    const int* dst = ei + E;
    float* out = (float*)d_out;

    const int nbin = (N + (1 << BSH) - 1) >> BSH;          // 391

    // ---- workspace layout (4-byte units, 256-aligned sections) ----
    const size_t Np = ((size_t)N + 256) & ~(size_t)255;
    const size_t Ep = ((size_t)E + 255) & ~(size_t)255;
    const size_t Fp = (((size_t)N * 32) + 255) & ~(size_t)255;   // N*64 bf16 in floats
    float* base = (float*)d_ws;
    size_t off = 0;
    int*      gcount  = (int*)(base + off);  off += MAXBIN;
    int*      gbase   = (int*)(base + off);  off += MAXBIN + 256;
    int*      gcur    = (int*)(base + off);  off += MAXBIN;
    int*      rp2     = (int*)(base + off);  off += 4 * Np + 256; // [4N+1]
    float*    dinv    =        base + off;   off += Np;
    unsigned* ebuf    = (unsigned*)(base + off); off += Ep;
    int*      csr_src = (int*)(base + off);  off += Ep;
    unsigned short* tb = (unsigned short*)(base + off); off += Fp;
    unsigned short* ab = (unsigned short*)(base + off); off += Fp;
    // total ~ 41 MB

    const int nchunk = (E + CH - 1) / CH;

    // ---- CSR build (also produces dinv, 4-way phase-bucketed lists) ----
    hipMemsetAsync(gcount, 0, MAXBIN * sizeof(int), stream);
    binA1<<<nchunk, 256, 0, stream>>>(dst, gcount, E, nbin);
    binscan<<<1, 512, 0, stream>>>(gcount, gbase, gcur, rp2, nbin, N, E);
    binA2<<<nchunk, 256, 0, stream>>>(src, dst, gcur, ebuf, E, nbin);
    binB<<<nbin, 256, 0, stream>>>(ebuf, gbase, rp2, dinv, csr_src, N);

    const int gBlocks = (N + 127) / 128;

    // ---- layer 1 ----
    lin_kernel<NFEAT, NHID, false, false><<<(N + 63) / 64, 256, 0, stream>>>(x, W1, nullptr, dinv, tb, N);
    gather64p<<<gBlocks, 256, 0, stream>>>(tb, dinv, rp2, csr_src, ab, N);

    // ---- layer 2 ----
    lin_kernel<NHID, NHID, true, true><<<(N + 63) / 64, 256, 0, stream>>>(ab, W2, b1, dinv, tb, N);
    gather64p<<<gBlocks, 256, 0, stream>>>(tb, dinv, rp2, csr_src, ab, N);

    // ---- layer 3 ----
    lin_kernel<NHID, NCLASS, true, true><<<(N + 99) / 100, 256, 0, stream>>>(ab, W3, b2, dinv, tb, N);
    gather40p_lsm<<<gBlocks, 256, 0, stream>>>(tb, dinv, rp2, csr_src, b3, out, N);
}

// Round 6
// 381.283 us; speedup vs baseline: 2.1704x; 2.1704x over previous
//
#include <hip/hip_runtime.h>

#define NFEAT 128
#define NHID 64
#define NCLASS 40

#define BSH 8                    // CSR-build bin = 256 nodes
#define MAXBIN 512               // supports N <= 131072
#define CH 8192                  // edges per chunk in pass A

// ---------------- bf16 helpers (storage-only precision; compute is fp32) ----------------

__device__ __forceinline__ float bfu(unsigned short u) {
    return __uint_as_float((unsigned)u << 16);
}
__device__ __forceinline__ unsigned short fbf(float f) {
    unsigned u = __float_as_uint(f);
    u += 0x7fffu + ((u >> 16) & 1u);        // round-to-nearest-even
    return (unsigned short)(u >> 16);
}
// unpack uint2 (4 packed bf16) -> float4
__device__ __forceinline__ float4 up4(uint2 u) {
    return make_float4(__uint_as_float(u.x << 16), __uint_as_float(u.x & 0xffff0000u),
                       __uint_as_float(u.y << 16), __uint_as_float(u.y & 0xffff0000u));
}

// ======================= CSR build, hierarchical =======================

__launch_bounds__(256)
__global__ void binA1(const int* __restrict__ dst, int* __restrict__ gcount, int E, int nbin) {
    __shared__ int h[MAXBIN];
    const int t = threadIdx.x;
    for (int i = t; i < nbin; i += 256) h[i] = 0;
    __syncthreads();
    const int e0 = blockIdx.x * CH;
    const int e1 = min(e0 + CH, E);
    for (int i = e0 + t; i < e1; i += 256) atomicAdd(&h[dst[i] >> BSH], 1);
    __syncthreads();
    for (int i = t; i < nbin; i += 256) { int c = h[i]; if (c) atomicAdd(&gcount[i], c); }
}

__launch_bounds__(512)
__global__ void binscan(const int* __restrict__ gcount, int* __restrict__ gbase,
                        int* __restrict__ gcur, int* __restrict__ row_ptr,
                        int nbin, int N, int E) {
    __shared__ int sd[512];
    const int t = threadIdx.x;
    int v = (t < nbin) ? gcount[t] : 0;
    sd[t] = v;
    __syncthreads();
    for (int off = 1; off < 512; off <<= 1) {
        int tmp = (t >= off) ? sd[t - off] : 0;
        __syncthreads();
        sd[t] += tmp;
        __syncthreads();
    }
    int excl = sd[t] - v;
    if (t < nbin) { gbase[t] = excl; gcur[t] = excl; }
    if (t == 0) { gbase[nbin] = E; row_ptr[N] = E; }
}

// A2: reserve a contiguous run per bin, scatter packed (local_dst<<24 | src).
__launch_bounds__(256)
__global__ void binA2(const int* __restrict__ src, const int* __restrict__ dst,
                      int* __restrict__ gcur, unsigned* __restrict__ ebuf, int E, int nbin) {
    __shared__ int h[MAXBIN];
    __shared__ int base[MAXBIN];
    const int t = threadIdx.x;
    for (int i = t; i < nbin; i += 256) h[i] = 0;
    __syncthreads();
    const int e0 = blockIdx.x * CH;
    const int e1 = min(e0 + CH, E);
    for (int i = e0 + t; i < e1; i += 256) atomicAdd(&h[dst[i] >> BSH], 1);
    __syncthreads();
    for (int i = t; i < nbin; i += 256) {
        int c = h[i];
        if (c) base[i] = atomicAdd(&gcur[i], c);
        h[i] = 0;
    }
    __syncthreads();
    for (int i = e0 + t; i < e1; i += 256) {
        int d = dst[i];
        int b = d >> BSH;
        int pos = base[b] + atomicAdd(&h[b], 1);
        ebuf[pos] = ((unsigned)(d & ((1 << BSH) - 1)) << 24) | (unsigned)src[i];
    }
}

// B: one wg per 256-node bin: LDS count -> scan -> row_ptr + dinv + csr scatter.
__launch_bounds__(256)
__global__ void binB(const unsigned* __restrict__ ebuf, const int* __restrict__ gbase,
                     int* __restrict__ row_ptr, float* __restrict__ dinv,
                     int* __restrict__ csr_src, int N) {
    __shared__ int cnt[256];
    __shared__ int sd[256];
    __shared__ int cur[256];
    const int b = blockIdx.x;
    const int n0 = b << BSH;
    const int t = threadIdx.x;
    const int b0 = gbase[b], b1 = gbase[b + 1];
    cnt[t] = 0;
    __syncthreads();
    for (int i = b0 + t; i < b1; i += 256) atomicAdd(&cnt[ebuf[i] >> 24], 1);
    __syncthreads();
    int v = cnt[t];
    sd[t] = v;
    __syncthreads();
    for (int off = 1; off < 256; off <<= 1) {
        int tmp = (t >= off) ? sd[t - off] : 0;
        __syncthreads();
        sd[t] += tmp;
        __syncthreads();
    }
    int excl = sd[t] - v;
    int n = n0 + t;
    if (n < N) {
        row_ptr[n] = b0 + excl;
        dinv[n] = rsqrtf((float)v + 1.0f);      // +1 self loop
    }
    cur[t] = b0 + excl;
    __syncthreads();
    for (int i = b0 + t; i < b1; i += 256) {
        unsigned p = ebuf[i];
        int pos = atomicAdd(&cur[p >> 24], 1);
        csr_src[pos] = (int)(p & 0xffffffu);
    }
}

// ======================= dense linear =======================
// out[n,:] = bf16( dinv[n] * (f(in[n,:]) @ W) ), f = relu(x + bias_prev) if RELU_BIAS.

template<int K, int F, bool RELU_BIAS, bool IN_BF16>
__launch_bounds__(256)
__global__ void lin_kernel(const void* __restrict__ in_, const float* __restrict__ W,
                           const float* __restrict__ bias, const float* __restrict__ dinv,
                           unsigned short* __restrict__ out, int N) {
    constexpr int FT = F / 4;
    constexpr int TG = 256 / FT;
    constexpr int NPT = 4;
    constexpr int NODES = TG * NPT;
    constexpr int KP = K + 4;

    __shared__ alignas(16) float Ws[K * F];
    __shared__ alignas(16) float xs[NODES * KP];

    const int tid = threadIdx.x;
    const int n0 = blockIdx.x * NODES;

    for (int q = tid; q < K * F / 4; q += 256)
        ((float4*)Ws)[q] = ((const float4*)W)[q];

    if constexpr (IN_BF16) {
        const unsigned short* in = (const unsigned short*)in_;
        for (int q = tid; q < NODES * (K / 8); q += 256) {
            int ni = q / (K / 8);
            int c = q - ni * (K / 8);
            int n = n0 + ni;
            float v[8];
            if (n < N) {
                uint4 raw = *(const uint4*)(in + (size_t)n * K + c * 8);
                unsigned rr[4] = {raw.x, raw.y, raw.z, raw.w};
                #pragma unroll
                for (int j = 0; j < 4; ++j) {
                    v[2 * j]     = __uint_as_float(rr[j] << 16);
                    v[2 * j + 1] = __uint_as_float(rr[j] & 0xffff0000u);
                }
            } else {
                #pragma unroll
                for (int j = 0; j < 8; ++j) v[j] = 0.f;
            }
            if constexpr (RELU_BIAS) {
                #pragma unroll
                for (int j = 0; j < 8; ++j) v[j] = fmaxf(v[j] + bias[c * 8 + j], 0.f);
            }
            *(float4*)&xs[ni * KP + c * 8]     = make_float4(v[0], v[1], v[2], v[3]);
            *(float4*)&xs[ni * KP + c * 8 + 4] = make_float4(v[4], v[5], v[6], v[7]);
        }
    } else {
        const float* in = (const float*)in_;
        for (int q = tid; q < NODES * (K / 4); q += 256) {
            int ni = q / (K / 4);
            int kq = q - ni * (K / 4);
            int n = n0 + ni;
            float4 v = make_float4(0.f, 0.f, 0.f, 0.f);
            if (n < N) v = ((const float4*)in)[(size_t)n * (K / 4) + kq];
            if constexpr (RELU_BIAS) {
                float4 b = ((const float4*)bias)[kq];
                v.x = fmaxf(v.x + b.x, 0.f);
                v.y = fmaxf(v.y + b.y, 0.f);
                v.z = fmaxf(v.z + b.z, 0.f);
                v.w = fmaxf(v.w + b.w, 0.f);
            }
            *(float4*)&xs[ni * KP + kq * 4] = v;
        }
    }
    __syncthreads();

    const int tx = tid % FT;
    const int tg = tid / FT;
    if (tg >= TG) return;

    float4 acc[NPT];
    #pragma unroll
    for (int i = 0; i < NPT; ++i) acc[i] = make_float4(0.f, 0.f, 0.f, 0.f);

    #pragma unroll 4
    for (int kq = 0; kq < K / 4; ++kq) {
        float4 w0 = *(const float4*)&Ws[(kq * 4 + 0) * F + tx * 4];
        float4 w1 = *(const float4*)&Ws[(kq * 4 + 1) * F + tx * 4];
        float4 w2 = *(const float4*)&Ws[(kq * 4 + 2) * F + tx * 4];
        float4 w3 = *(const float4*)&Ws[(kq * 4 + 3) * F + tx * 4];
        #pragma unroll
        for (int i = 0; i < NPT; ++i) {
            float4 xv = *(const float4*)&xs[(tg * NPT + i) * KP + kq * 4];
            acc[i].x += xv.x * w0.x + xv.y * w1.x + xv.z * w2.x + xv.w * w3.x;
            acc[i].y += xv.x * w0.y + xv.y * w1.y + xv.z * w2.y + xv.w * w3.y;
            acc[i].z += xv.x * w0.z + xv.y * w1.z + xv.z * w2.z + xv.w * w3.z;
            acc[i].w += xv.x * w0.w + xv.y * w1.w + xv.z * w2.w + xv.w * w3.w;
        }
    }

    #pragma unroll
    for (int i = 0; i < NPT; ++i) {
        int n = n0 + tg * NPT + i;
        if (n < N) {
            float d = dinv[n];
            ushort4 o;
            o.x = fbf(acc[i].x * d);
            o.y = fbf(acc[i].y * d);
            o.z = fbf(acc[i].z * d);
            o.w = fbf(acc[i].w * d);
            *(ushort4*)(out + (size_t)n * F + tx * 4) = o;
        }
    }
}

// ======================= wide gather: 4 edges per wave-instruction =======================
// One wave per dst node. Lanes = 4 groups x 16 feature-quads; lane loads uint2
// (4 bf16) of its group's source row -> 1 feature load + 1 csr load serve 4
// edges (~2.5 VALU/edge vs ~10 scalar). Group partials combined once per node
// via shfl_xor(16,32).

__launch_bounds__(256)
__global__ void gather64w(const unsigned short* __restrict__ g, const float* __restrict__ dinv,
                          const int* __restrict__ row_ptr, const int* __restrict__ csr_src,
                          unsigned short* __restrict__ out, int N) {
    int gid = blockIdx.x * blockDim.x + threadIdx.x;
    int n = gid >> 6;
    int lane = gid & 63;
    if (n >= N) return;
    const int grp = lane >> 4;          // edge slot 0..3
    const int fq  = lane & 15;          // feature quad: features 4*fq..4*fq+3

    int e0 = row_ptr[n], e1 = row_ptr[n + 1];

    // self loop (group 0 only; other groups start at zero)
    float4 acc = make_float4(0.f, 0.f, 0.f, 0.f);
    {
        uint2 u = *(const uint2*)(g + (size_t)n * 64 + fq * 4);
        if (grp == 0) acc = up4(u);
    }

    int e = e0;
    for (; e + 8 <= e1; e += 8) {       // two independent 4-edge chains
        int sA = csr_src[e + grp];
        int sB = csr_src[e + 4 + grp];
        uint2 uA = *(const uint2*)(g + (size_t)sA * 64 + fq * 4);
        uint2 uB = *(const uint2*)(g + (size_t)sB * 64 + fq * 4);
        float4 a = up4(uA), b = up4(uB);
        acc.x += a.x + b.x; acc.y += a.y + b.y;
        acc.z += a.z + b.z; acc.w += a.w + b.w;
    }
    if (e + 4 <= e1) {
        int s = csr_src[e + grp];
        uint2 u = *(const uint2*)(g + (size_t)s * 64 + fq * 4);
        float4 a = up4(u);
        acc.x += a.x; acc.y += a.y; acc.z += a.z; acc.w += a.w;
        e += 4;
    }
    int m = e1 - e;                     // 0..3 remaining
    if (m > 0) {
        int s = csr_src[(e + grp < e1) ? e + grp : e1 - 1];
        uint2 u = *(const uint2*)(g + (size_t)s * 64 + fq * 4);
        if (grp < m) {
            float4 a = up4(u);
            acc.x += a.x; acc.y += a.y; acc.z += a.z; acc.w += a.w;
        }
    }

    // combine the 4 group partials (same fq across lanes l, l+16, l+32, l+48)
    #pragma unroll
    for (int off = 16; off <= 32; off <<= 1) {
        acc.x += __shfl_xor(acc.x, off, 64);
        acc.y += __shfl_xor(acc.y, off, 64);
        acc.z += __shfl_xor(acc.z, off, 64);
        acc.w += __shfl_xor(acc.w, off, 64);
    }

    if (grp == 0) {
        float d = dinv[n];
        ushort4 o;
        o.x = fbf(acc.x * d); o.y = fbf(acc.y * d);
        o.z = fbf(acc.z * d); o.w = fbf(acc.w * d);
        *(ushort4*)(out + (size_t)n * 64 + fq * 4) = o;
    }
}

// Layer-3: wide gather on 40-wide rows (quads 0..9 active) + fused bias + log_softmax.
__launch_bounds__(256)
__global__ void gather40w_lsm(const unsigned short* __restrict__ g, const float* __restrict__ dinv,
                              const int* __restrict__ row_ptr, const int* __restrict__ csr_src,
                              const float* __restrict__ b3, float* __restrict__ out, int N) {
    int gid = blockIdx.x * blockDim.x + threadIdx.x;
    int n = gid >> 6;
    int lane = gid & 63;
    if (n >= N) return;
    const int grp = lane >> 4;
    const int fq  = lane & 15;          // quads 0..9 hold the 40 classes

    int e0 = row_ptr[n], e1 = row_ptr[n + 1];

    float4 acc = make_float4(0.f, 0.f, 0.f, 0.f);
    {
        uint2 u = *(const uint2*)(g + (size_t)n * NCLASS + fq * 4);   // fq>=10 reads junk, masked later
        if (grp == 0) acc = up4(u);
    }

    int e = e0;
    for (; e + 8 <= e1; e += 8) {
        int sA = csr_src[e + grp];
        int sB = csr_src[e + 4 + grp];
        uint2 uA = *(const uint2*)(g + (size_t)sA * NCLASS + fq * 4);
        uint2 uB = *(const uint2*)(g + (size_t)sB * NCLASS + fq * 4);
        float4 a = up4(uA), b = up4(uB);
        acc.x += a.x + b.x; acc.y += a.y + b.y;
        acc.z += a.z + b.z; acc.w += a.w + b.w;
    }
    if (e + 4 <= e1) {
        int s = csr_src[e + grp];
        uint2 u = *(const uint2*)(g + (size_t)s * NCLASS + fq * 4);
        float4 a = up4(u);
        acc.x += a.x; acc.y += a.y; acc.z += a.z; acc.w += a.w;
        e += 4;
    }
    int m = e1 - e;
    if (m > 0) {
        int s = csr_src[(e + grp < e1) ? e + grp : e1 - 1];
        uint2 u = *(const uint2*)(g + (size_t)s * NCLASS + fq * 4);
        if (grp < m) {
            float4 a = up4(u);
            acc.x += a.x; acc.y += a.y; acc.z += a.z; acc.w += a.w;
        }
    }

    #pragma unroll
    for (int off = 16; off <= 32; off <<= 1) {
        acc.x += __shfl_xor(acc.x, off, 64);
        acc.y += __shfl_xor(acc.y, off, 64);
        acc.z += __shfl_xor(acc.z, off, 64);
        acc.w += __shfl_xor(acc.w, off, 64);
    }

    // bias + log_softmax over the 40 classes (float4 per quad, all lanes have
    // their fq's totals; quads >= 10 masked to -inf / 0)
    float d = dinv[n];
    float4 b = *(const float4*)(b3 + fq * 4);   // b3 has 64 entries -> fq*4+3 <= 63 safe
    float4 v = make_float4(acc.x * d + b.x, acc.y * d + b.y,
                           acc.z * d + b.z, acc.w * d + b.w);
    float lm = (fq < 10) ? fmaxf(fmaxf(v.x, v.y), fmaxf(v.z, v.w)) : -1e30f;
    #pragma unroll
    for (int off = 1; off < 16; off <<= 1)
        lm = fmaxf(lm, __shfl_xor(lm, off, 64));
    float ls = (fq < 10) ? (expf(v.x - lm) + expf(v.y - lm) + expf(v.z - lm) + expf(v.w - lm)) : 0.f;
    #pragma unroll
    for (int off = 1; off < 16; off <<= 1)
        ls += __shfl_xor(ls, off, 64);
    float lg = lm + logf(ls);
    if (grp == 0 && fq < 10) {
        float4 o = make_float4(v.x - lg, v.y - lg, v.z - lg, v.w - lg);
        *(float4*)(out + (size_t)n * NCLASS + fq * 4) = o;
    }
}

// ======================= launch =======================

extern "C" void kernel_launch(void* const* d_in, const int* in_sizes, int n_in,
                              void* d_out, int out_size, void* d_ws, size_t ws_size,
                              hipStream_t stream) {
    const float* x  = (const float*)d_in[0];
    const int*   ei = (const int*)  d_in[1];
    const float* W1 = (const float*)d_in[2];
    const float* b1 = (const float*)d_in[3];
    const float* W2 = (const float*)d_in[4];
    const float* b2 = (const float*)d_in[5];
    const float* W3 = (const float*)d_in[6];
    const float* b3 = (const float*)d_in[7];
    const int N = in_sizes[0] / NFEAT;
    const int E = in_sizes[1] / 2;
    const int* src = ei;
    const int* dst = ei + E;
    float* out = (float*)d_out;

    const int nbin = (N + (1 << BSH) - 1) >> BSH;          // 391

    // ---- workspace layout (4-byte units, 256-aligned sections) ----
    const size_t Np = ((size_t)N + 256) & ~(size_t)255;
    const size_t Ep = ((size_t)E + 255) & ~(size_t)255;
    const size_t Fp = (((size_t)N * 32) + 255) & ~(size_t)255;   // N*64 bf16 in floats
    float* base = (float*)d_ws;
    size_t off = 0;
    int*      gcount  = (int*)(base + off);  off += MAXBIN;
    int*      gbase   = (int*)(base + off);  off += MAXBIN + 256;
    int*      gcur    = (int*)(base + off);  off += MAXBIN;
    int*      row_ptr = (int*)(base + off);  off += Np;
    float*    dinv    =        base + off;   off += Np;
    unsigned* ebuf    = (unsigned*)(base + off); off += Ep;
    int*      csr_src = (int*)(base + off);  off += Ep;
    unsigned short* tb = (unsigned short*)(base + off); off += Fp;
    unsigned short* ab = (unsigned short*)(base + off); off += Fp;
    // total ~ 39 MB

    const int nchunk = (E + CH - 1) / CH;

    // ---- CSR build (also produces dinv) ----
    hipMemsetAsync(gcount, 0, MAXBIN * sizeof(int), stream);
    binA1<<<nchunk, 256, 0, stream>>>(dst, gcount, E, nbin);
    binscan<<<1, 512, 0, stream>>>(gcount, gbase, gcur, row_ptr, nbin, N, E);
    binA2<<<nchunk, 256, 0, stream>>>(src, dst, gcur, ebuf, E, nbin);
    binB<<<nbin, 256, 0, stream>>>(ebuf, gbase, row_ptr, dinv, csr_src, N);

    const int gatherBlocks = (int)(((size_t)N * 64 + 255) / 256);

    // ---- layer 1 ----
    lin_kernel<NFEAT, NHID, false, false><<<(N + 63) / 64, 256, 0, stream>>>(x, W1, nullptr, dinv, tb, N);
    gather64w<<<gatherBlocks, 256, 0, stream>>>(tb, dinv, row_ptr, csr_src, ab, N);

    // ---- layer 2 ----
    lin_kernel<NHID, NHID, true, true><<<(N + 63) / 64, 256, 0, stream>>>(ab, W2, b1, dinv, tb, N);
    gather64w<<<gatherBlocks, 256, 0, stream>>>(tb, dinv, row_ptr, csr_src, ab, N);

    // ---- layer 3 ----
    lin_kernel<NHID, NCLASS, true, true><<<(N + 99) / 100, 256, 0, stream>>>(ab, W3, b2, dinv, tb, N);
    gather40w_lsm<<<gatherBlocks, 256, 0, stream>>>(tb, dinv, row_ptr, csr_src, b3, out, N);
}